// Round 6
// baseline (204.411 us; speedup 1.0000x reference)
//
#include <hip/hip_runtime.h>
#include <hip/hip_bf16.h>

// GMM log-likelihood, N=65536, K=32, F=128.
// Hybrid split: wave (gh,nh) owns 64 g-rows (g-tiles gh*2, gh*2+1) and 64
// n-rows (n-tiles nh*2 .. but addressed as t=0,1 within its nh half), so each
// A-frag ds_read feeds 2 MFMAs: 16 reads -> 32 MFMAs per comp per wave.
// Mean fold via v-trick: logprob = sum y^2 - 2*x.v_k + sum mp^2 (xv from an
// 8-MFMA prologue mini-GEMM; compile-time reg index via full K unroll).
// Pairwise cross-wave combine: wave finalizes n-tile t==gh, exchanges the
// other partial with wave wid^1 through a 1-float LDS slot. 1 barrier/comp.

#define NPTS 65536
#define KC 32
#define FD 128
#define SLABB 32768  // 4 q * 8 s * 64 lanes * 16 B per component

typedef __attribute__((ext_vector_type(8))) short short8;
typedef __attribute__((ext_vector_type(8))) unsigned short ushort8;
typedef __attribute__((ext_vector_type(16))) float f32x16;

static __device__ __forceinline__ unsigned short f2bf(float f) {
  unsigned int u = __float_as_uint(f);
  u += 0x7FFFu + ((u >> 16) & 1u);  // RNE
  return (unsigned short)(u >> 16);
}

// --- prep1: mp[k][g] = sum_f means[k][f]*P[k][f][g];
//     ck3[k] = log w + logdet - 0.5*(F*log2pi + sum_g mp^2) ---
__global__ void prep1(const float* __restrict__ means, const float* __restrict__ P,
                      const float* __restrict__ w, float* __restrict__ mp,
                      float* __restrict__ ck3) {
  int k = blockIdx.x, g = threadIdx.x;  // 32 x 128
  const float* Pk = P + k * FD * FD;
  float acc = 0.f;
  for (int f = 0; f < FD; ++f) acc = fmaf(means[k * FD + f], Pk[f * FD + g], acc);
  mp[k * FD + g] = acc;
  __shared__ float r1[FD], r2[FD];
  r1[g] = logf(Pk[g * FD + g]);
  r2[g] = acc * acc;
  __syncthreads();
  for (int off = 64; off; off >>= 1) {
    if (g < off) { r1[g] += r1[g + off]; r2[g] += r2[g + off]; }
    __syncthreads();
  }
  if (g == 0)
    ck3[k] = logf(w[k]) + r1[0] - 0.5f * ((float)FD * 1.8378770664093453f + r2[0]);
}

// --- prep2: v[k][f] = sum_g P[k][f][g] * mp[k][g] ---
__global__ void prep2(const float* __restrict__ P, const float* __restrict__ mp,
                      float* __restrict__ v) {
  int k = blockIdx.x, f = threadIdx.x;  // 32 x 128
  __shared__ float smp[FD];
  smp[f] = mp[k * FD + f];
  __syncthreads();
  const float* Pr = P + k * FD * FD + f * FD;
  float acc = 0.f;
  for (int g = 0; g < FD; ++g) acc = fmaf(Pr[g], smp[g], acc);
  v[k * FD + f] = acc;
}

// --- prep3: xv mini-slab (8 KB): A'[row k][f] = v[k][f], frag-major ---
__global__ void prep3(const float* __restrict__ v, unsigned char* __restrict__ Ximg) {
  int id = blockIdx.x * 256 + threadIdx.x;  // 0..511 chunks
  int l = id & 63, s = id >> 6;
  int r = l & 31, f0 = 16 * s + 8 * (l >> 5);
  ushort8 o;
#pragma unroll
  for (int j = 0; j < 8; ++j) o[j] = f2bf(v[r * FD + f0 + j]);
  *(ushort8*)(Ximg + (size_t)id * 16) = o;
}

// --- prep4: frag-major bf16 A image. chunk id -> (k,q,s,lane). ---
__global__ void prep4(const float* __restrict__ P, unsigned char* __restrict__ Aimg) {
  int id = blockIdx.x * 256 + threadIdx.x;  // 0..65535
  int l = id & 63;
  int s = (id >> 6) & 7;
  int q = (id >> 9) & 3;
  int k = id >> 11;
  int g = q * 32 + (l & 31);
  int f0 = 16 * s + 8 * (l >> 5);
  ushort8 o;
#pragma unroll
  for (int j = 0; j < 8; ++j) o[j] = f2bf(P[k * 16384 + (f0 + j) * 128 + g]);
  *(ushort8*)(Aimg + (size_t)id * 16) = o;
}

// --- main ---
template <int K>
__device__ __forceinline__ void comp_iter(const unsigned char* __restrict__ Aimg,
                                          unsigned char* abuf, float (&xch)[2][4][32],
                                          const float* ck, int wid, int gh, int lane,
                                          int half, int ln, const short8 (&xf)[2][8],
                                          const f32x16& xv, float& m, float& ssum) {
  constexpr int RB = (K & 1) * SLABB;
  constexpr int WB = SLABB - RB;
  constexpr int PH = K & 1;
  if constexpr (K + 1 < KC) {
    // stage slab K+1 into the other buffer (its readers finished last comp)
    const unsigned char* gs = Aimg + (size_t)(K + 1) * SLABB + wid * 8192 + lane * 16;
    unsigned char* ls = abuf + WB + wid * 8192;
#pragma unroll
    for (int i = 0; i < 8; ++i)
      __builtin_amdgcn_global_load_lds(
          (const __attribute__((address_space(1))) void*)(gs + i * 1024),
          (__attribute__((address_space(3))) void*)(ls + i * 1024), 16, 0, 0);
  }
  // read this wave's 2 g-tiles (16 frags); each frag feeds 2 MFMAs
  const unsigned char* rb = abuf + RB + gh * 16384 + lane * 16;
  short8 fr[16];
#pragma unroll
  for (int g2 = 0; g2 < 2; ++g2)
#pragma unroll
    for (int s = 0; s < 8; ++s) fr[g2 * 8 + s] = *(const short8*)(rb + g2 * 8192 + s * 1024);
  f32x16 a00, a01, a10, a11;
#pragma unroll
  for (int i = 0; i < 16; ++i) { a00[i] = 0.f; a01[i] = 0.f; a10[i] = 0.f; a11[i] = 0.f; }
  __builtin_amdgcn_s_setprio(1);
#pragma unroll
  for (int s = 0; s < 8; ++s) {
    a00 = __builtin_amdgcn_mfma_f32_32x32x16_bf16(fr[s], xf[0][s], a00, 0, 0, 0);
    a01 = __builtin_amdgcn_mfma_f32_32x32x16_bf16(fr[s], xf[1][s], a01, 0, 0, 0);
  }
#pragma unroll
  for (int s = 0; s < 8; ++s) {
    a10 = __builtin_amdgcn_mfma_f32_32x32x16_bf16(fr[8 + s], xf[0][s], a10, 0, 0, 0);
    a11 = __builtin_amdgcn_mfma_f32_32x32x16_bf16(fr[8 + s], xf[1][s], a11, 0, 0, 0);
  }
  __builtin_amdgcn_s_setprio(0);
  // epilogue: per-tile squares over this wave's 64 g
  float s0a = 0.f, s0b = 0.f, s1a = 0.f, s1b = 0.f;
#pragma unroll
  for (int i = 0; i < 16; ++i) {
    s0a = fmaf(a00[i], a00[i], s0a);
    s0b = fmaf(a10[i], a10[i], s0b);
    s1a = fmaf(a01[i], a01[i], s1a);
    s1b = fmaf(a11[i], a11[i], s1b);
  }
  float s0 = s0a + s0b, s1 = s1a + s1b;
  s0 += __shfl_xor(s0, 32, 64);  // both halves now hold full-64g partials
  s1 += __shfl_xor(s1, 32, 64);
  float sown = gh ? s1 : s0;   // tile this wave finalizes (t == gh)
  float soth = gh ? s0 : s1;   // tile the partner finalizes
  if (half == 0) xch[PH][wid ^ 1][ln] = soth;  // deliver to partner's slot
  if constexpr (K + 1 < KC) asm volatile("s_waitcnt vmcnt(0)" ::: "memory");
  __syncthreads();
  float sfull = sown + xch[PH][wid][ln];  // + partner's 64 g for tile t==gh
  // -2 * x.v_K, made half-uniform with one shfl
  constexpr int owner = (K >> 2) & 1;
  constexpr int idx = (K & 3) | ((K >> 3) << 2);
  float tx = (half == owner) ? xv[idx] : 0.f;
  tx += __shfl_xor(tx, 32, 64);
  sfull = fmaf(-2.f, tx, sfull);
  float vv = ck[K] - 0.5f * sfull;
  float nm = fmaxf(m, vv);
  ssum = ssum * __expf(m - nm) + __expf(vv - nm);
  m = nm;
  if constexpr (K + 1 < KC)
    comp_iter<K + 1>(Aimg, abuf, xch, ck, wid, gh, lane, half, ln, xf, xv, m, ssum);
}

__global__ __launch_bounds__(256, 2) void gmm_main(const float* __restrict__ x,
                                                   const unsigned char* __restrict__ Aimg,
                                                   const unsigned char* __restrict__ Ximg,
                                                   const float* __restrict__ ck3,
                                                   float* __restrict__ out) {
  __shared__ __align__(16) unsigned char abuf[2 * SLABB];
  __shared__ __align__(16) float xch[2][4][32];
  __shared__ float ck[KC];
  const int tid = threadIdx.x;
  const int wid = tid >> 6;
  const int lane = tid & 63;
  const int half = lane >> 5;
  const int ln = lane & 31;
  const int gh = wid & 1;   // g-half this wave owns (g-tiles gh*2, gh*2+1)
  const int nh = wid >> 1;  // n-half this wave owns (64 x-rows)
  const int nbase = blockIdx.x * 128;

  if (tid < KC) ck[tid] = ck3[tid];

  // issue prologue stages: xv mini-slab -> buf1[0:8K], slab0 -> buf0
  {
    const unsigned char* gx = Ximg + wid * 2048 + lane * 16;
    unsigned char* lx = abuf + SLABB + wid * 2048;
    __builtin_amdgcn_global_load_lds((const __attribute__((address_space(1))) void*)gx,
                                     (__attribute__((address_space(3))) void*)lx, 16, 0, 0);
    __builtin_amdgcn_global_load_lds(
        (const __attribute__((address_space(1))) void*)(gx + 1024),
        (__attribute__((address_space(3))) void*)(lx + 1024), 16, 0, 0);
    const unsigned char* gs = Aimg + wid * 8192 + lane * 16;
    unsigned char* ls = abuf + wid * 8192;
#pragma unroll
    for (int i = 0; i < 8; ++i)
      __builtin_amdgcn_global_load_lds(
          (const __attribute__((address_space(1))) void*)(gs + i * 1024),
          (__attribute__((address_space(3))) void*)(ls + i * 1024), 16, 0, 0);
  }

  // B fragments: this wave's 64 x-rows (2 n-tiles), resident all kernel.
  // xf[t][s][j] = x[nbase + nh*64 + t*32 + ln][16s + 8*half + j]
  short8 xf[2][8];
#pragma unroll
  for (int t = 0; t < 2; ++t) {
    const float* xr = x + (size_t)(nbase + nh * 64 + t * 32 + ln) * FD + 8 * half;
#pragma unroll
    for (int s = 0; s < 8; ++s) {
      const float4 a = *(const float4*)(xr + 16 * s);
      const float4 b = *(const float4*)(xr + 16 * s + 4);
      short8 f;
      f[0] = (short)f2bf(a.x); f[1] = (short)f2bf(a.y);
      f[2] = (short)f2bf(a.z); f[3] = (short)f2bf(a.w);
      f[4] = (short)f2bf(b.x); f[5] = (short)f2bf(b.y);
      f[6] = (short)f2bf(b.z); f[7] = (short)f2bf(b.w);
      xf[t][s] = f;
    }
  }

  asm volatile("s_waitcnt vmcnt(0)" ::: "memory");
  __syncthreads();

  // xv[n,k] mini-GEMM for the tile this wave finalizes (t == gh):
  // row k = (i&3)+8*(i>>2)+4*half, col n = nbase + nh*64 + gh*32 + ln
  f32x16 xv;
#pragma unroll
  for (int i = 0; i < 16; ++i) xv[i] = 0.f;
  {
    short8 xg[8];
#pragma unroll
    for (int s = 0; s < 8; ++s) xg[s] = gh ? xf[1][s] : xf[0][s];
    const unsigned char* xb = abuf + SLABB + lane * 16;
#pragma unroll
    for (int s = 0; s < 8; ++s) {
      const short8 fx = *(const short8*)(xb + s * 1024);
      xv = __builtin_amdgcn_mfma_f32_32x32x16_bf16(fx, xg[s], xv, 0, 0, 0);
    }
  }
  asm volatile("s_waitcnt vmcnt(0) lgkmcnt(0)" ::: "memory");
  __syncthreads();  // xv region of buf1 free for reuse; slab0 resident

  float m = -__builtin_inff(), ssum = 0.f;
  comp_iter<0>(Aimg, abuf, xch, ck, wid, gh, lane, half, ln, xf, xv, m, ssum);

  if (half == 0) out[nbase + nh * 64 + gh * 32 + ln] = m + logf(ssum);
}

extern "C" void kernel_launch(void* const* d_in, const int* in_sizes, int n_in,
                              void* d_out, int out_size, void* d_ws, size_t ws_size,
                              hipStream_t stream) {
  const float* x = (const float*)d_in[0];
  const float* means = (const float*)d_in[1];
  const float* P = (const float*)d_in[2];
  const float* w = (const float*)d_in[3];
  float* out = (float*)d_out;

  unsigned char* ws = (unsigned char*)d_ws;
  unsigned char* Aimg = ws;                       // 1048576 B
  unsigned char* Ximg = ws + 1048576;             // 8192 B
  float* mp = (float*)(ws + 1048576 + 8192);      // 16384 B
  float* v = (float*)(ws + 1048576 + 24576);      // 16384 B
  float* ck3 = (float*)(ws + 1048576 + 40960);    // 128 B

  prep1<<<32, 128, 0, stream>>>(means, P, w, mp, ck3);
  prep2<<<32, 128, 0, stream>>>(P, mp, v);
  prep3<<<2, 256, 0, stream>>>(v, Ximg);
  prep4<<<256, 256, 0, stream>>>(P, Aimg);
  gmm_main<<<NPTS / 128, 256, 0, stream>>>(x, Aimg, Ximg, ck3, out);
}

// Round 7
// 189.221 us; speedup vs baseline: 1.0803x; 1.0803x over previous
//
#include <hip/hip_runtime.h>
#include <hip/hip_bf16.h>

// GMM log-likelihood, N=65536, K=32, F=128.
// Hybrid split: wave (gh,nh) owns 64 g-rows (2 g-tiles) x 64 n-rows (2
// n-tiles): 16 ds_read_b128 -> 32 MFMAs per comp per wave (LDS pipe ~2050 cyc
// ~= MFMA pipe 2065 cyc per CU per comp -- balanced). Register plan capped at
// ~200/lane (budget 256 = 128 VGPR + 128 AGPR at 2 waves/SIMD): single fr[8]
// frag bank reused across the two g-tiles. Mean fold via v-trick. Pairwise
// cross-wave combine through 1-float LDS slots. 1 barrier/comp.

#define NPTS 65536
#define KC 32
#define FD 128
#define SLABB 32768  // 4 q * 8 s * 64 lanes * 16 B per component

typedef __attribute__((ext_vector_type(8))) short short8;
typedef __attribute__((ext_vector_type(8))) unsigned short ushort8;
typedef __attribute__((ext_vector_type(16))) float f32x16;

static __device__ __forceinline__ unsigned short f2bf(float f) {
  unsigned int u = __float_as_uint(f);
  u += 0x7FFFu + ((u >> 16) & 1u);  // RNE
  return (unsigned short)(u >> 16);
}

// --- prep1: mp[k][g] = sum_f means[k][f]*P[k][f][g];
//     ck3[k] = log w + logdet - 0.5*(F*log2pi + sum_g mp^2) ---
__global__ void prep1(const float* __restrict__ means, const float* __restrict__ P,
                      const float* __restrict__ w, float* __restrict__ mp,
                      float* __restrict__ ck3) {
  int k = blockIdx.x, g = threadIdx.x;  // 32 x 128
  const float* Pk = P + k * FD * FD;
  float acc = 0.f;
  for (int f = 0; f < FD; ++f) acc = fmaf(means[k * FD + f], Pk[f * FD + g], acc);
  mp[k * FD + g] = acc;
  __shared__ float r1[FD], r2[FD];
  r1[g] = logf(Pk[g * FD + g]);
  r2[g] = acc * acc;
  __syncthreads();
  for (int off = 64; off; off >>= 1) {
    if (g < off) { r1[g] += r1[g + off]; r2[g] += r2[g + off]; }
    __syncthreads();
  }
  if (g == 0)
    ck3[k] = logf(w[k]) + r1[0] - 0.5f * ((float)FD * 1.8378770664093453f + r2[0]);
}

// --- prep2: v[k][f] = sum_g P[k][f][g] * mp[k][g] ---
__global__ void prep2(const float* __restrict__ P, const float* __restrict__ mp,
                      float* __restrict__ v) {
  int k = blockIdx.x, f = threadIdx.x;  // 32 x 128
  __shared__ float smp[FD];
  smp[f] = mp[k * FD + f];
  __syncthreads();
  const float* Pr = P + k * FD * FD + f * FD;
  float acc = 0.f;
  for (int g = 0; g < FD; ++g) acc = fmaf(Pr[g], smp[g], acc);
  v[k * FD + f] = acc;
}

// --- prep3: xv mini-slab (8 KB): A'[row k][f] = v[k][f], frag-major ---
__global__ void prep3(const float* __restrict__ v, unsigned char* __restrict__ Ximg) {
  int id = blockIdx.x * 256 + threadIdx.x;  // 0..511 chunks
  int l = id & 63, s = id >> 6;
  int r = l & 31, f0 = 16 * s + 8 * (l >> 5);
  ushort8 o;
#pragma unroll
  for (int j = 0; j < 8; ++j) o[j] = f2bf(v[r * FD + f0 + j]);
  *(ushort8*)(Ximg + (size_t)id * 16) = o;
}

// --- prep4: frag-major bf16 A image. chunk id -> (k,q,s,lane). ---
__global__ void prep4(const float* __restrict__ P, unsigned char* __restrict__ Aimg) {
  int id = blockIdx.x * 256 + threadIdx.x;  // 0..65535
  int l = id & 63;
  int s = (id >> 6) & 7;
  int q = (id >> 9) & 3;
  int k = id >> 11;
  int g = q * 32 + (l & 31);
  int f0 = 16 * s + 8 * (l >> 5);
  ushort8 o;
#pragma unroll
  for (int j = 0; j < 8; ++j) o[j] = f2bf(P[k * 16384 + (f0 + j) * 128 + g]);
  *(ushort8*)(Aimg + (size_t)id * 16) = o;
}

// --- main ---
template <int K>
__device__ __forceinline__ void comp_iter(const unsigned char* __restrict__ Aimg,
                                          unsigned char* abuf, float (&xch)[2][4][32],
                                          const float* ck, int wid, int gh, int lane,
                                          int half, int ln, const short8 (&xf)[2][8],
                                          const f32x16& xv, float& m, float& ssum) {
  constexpr int RB = (K & 1) * SLABB;
  constexpr int WB = SLABB - RB;
  constexpr int PH = K & 1;
  if constexpr (K + 1 < KC) {
    // stage slab K+1 into the other buffer (its readers finished last comp)
    const unsigned char* gs = Aimg + (size_t)(K + 1) * SLABB + wid * 8192 + lane * 16;
    unsigned char* ls = abuf + WB + wid * 8192;
#pragma unroll
    for (int i = 0; i < 8; ++i)
      __builtin_amdgcn_global_load_lds(
          (const __attribute__((address_space(1))) void*)(gs + i * 1024),
          (__attribute__((address_space(3))) void*)(ls + i * 1024), 16, 0, 0);
  }
  const unsigned char* rb = abuf + RB + gh * 16384 + lane * 16;
  f32x16 a00, a01, a10, a11;
#pragma unroll
  for (int i = 0; i < 16; ++i) { a00[i] = 0.f; a01[i] = 0.f; a10[i] = 0.f; a11[i] = 0.f; }
  // single 8-frag register bank, reused across the two g-tiles (reg budget)
  short8 fr[8];
#pragma unroll
  for (int s = 0; s < 8; ++s) fr[s] = *(const short8*)(rb + s * 1024);
  __builtin_amdgcn_s_setprio(1);
#pragma unroll
  for (int s = 0; s < 8; ++s) {
    a00 = __builtin_amdgcn_mfma_f32_32x32x16_bf16(fr[s], xf[0][s], a00, 0, 0, 0);
    a01 = __builtin_amdgcn_mfma_f32_32x32x16_bf16(fr[s], xf[1][s], a01, 0, 0, 0);
  }
#pragma unroll
  for (int s = 0; s < 8; ++s) fr[s] = *(const short8*)(rb + 8192 + s * 1024);
#pragma unroll
  for (int s = 0; s < 8; ++s) {
    a10 = __builtin_amdgcn_mfma_f32_32x32x16_bf16(fr[s], xf[0][s], a10, 0, 0, 0);
    a11 = __builtin_amdgcn_mfma_f32_32x32x16_bf16(fr[s], xf[1][s], a11, 0, 0, 0);
  }
  __builtin_amdgcn_s_setprio(0);
  // epilogue: per-n-tile squares over this wave's 64 g
  float s0a = 0.f, s0b = 0.f, s1a = 0.f, s1b = 0.f;
#pragma unroll
  for (int i = 0; i < 16; ++i) {
    s0a = fmaf(a00[i], a00[i], s0a);
    s0b = fmaf(a10[i], a10[i], s0b);
    s1a = fmaf(a01[i], a01[i], s1a);
    s1b = fmaf(a11[i], a11[i], s1b);
  }
  float s0 = s0a + s0b, s1 = s1a + s1b;
  s0 += __shfl_xor(s0, 32, 64);  // both halves now hold full-64g partials
  s1 += __shfl_xor(s1, 32, 64);
  float sown = gh ? s1 : s0;   // n-tile this wave finalizes (t == gh)
  float soth = gh ? s0 : s1;   // n-tile the partner finalizes
  if (half == 0) xch[PH][wid ^ 1][ln] = soth;  // deliver to partner's slot
  if constexpr (K + 1 < KC) asm volatile("s_waitcnt vmcnt(0)" ::: "memory");
  __syncthreads();
  float sfull = sown + xch[PH][wid][ln];  // + partner's 64 g for tile t==gh
  // -2 * x.v_K, made half-uniform with one shfl
  constexpr int owner = (K >> 2) & 1;
  constexpr int idx = (K & 3) | ((K >> 3) << 2);
  float tx = (half == owner) ? xv[idx] : 0.f;
  tx += __shfl_xor(tx, 32, 64);
  sfull = fmaf(-2.f, tx, sfull);
  float vv = ck[K] - 0.5f * sfull;
  float nm = fmaxf(m, vv);
  ssum = ssum * __expf(m - nm) + __expf(vv - nm);
  m = nm;
  if constexpr (K + 1 < KC)
    comp_iter<K + 1>(Aimg, abuf, xch, ck, wid, gh, lane, half, ln, xf, xv, m, ssum);
}

__global__ __launch_bounds__(256, 2) void gmm_main(const float* __restrict__ x,
                                                   const unsigned char* __restrict__ Aimg,
                                                   const unsigned char* __restrict__ Ximg,
                                                   const float* __restrict__ ck3,
                                                   float* __restrict__ out) {
  __shared__ __align__(16) unsigned char abuf[2 * SLABB];
  __shared__ __align__(16) float xch[2][4][32];
  __shared__ float ck[KC];
  const int tid = threadIdx.x;
  const int wid = tid >> 6;
  const int lane = tid & 63;
  const int half = lane >> 5;
  const int ln = lane & 31;
  const int gh = wid & 1;   // g-half this wave owns (g-tiles gh*2, gh*2+1)
  const int nh = wid >> 1;  // n-half this wave owns (64 x-rows)
  const int nbase = blockIdx.x * 128;

  if (tid < KC) ck[tid] = ck3[tid];

  // issue prologue stages: xv mini-slab -> buf1[0:8K], slab0 -> buf0
  {
    const unsigned char* gx = Ximg + wid * 2048 + lane * 16;
    unsigned char* lx = abuf + SLABB + wid * 2048;
    __builtin_amdgcn_global_load_lds((const __attribute__((address_space(1))) void*)gx,
                                     (__attribute__((address_space(3))) void*)lx, 16, 0, 0);
    __builtin_amdgcn_global_load_lds(
        (const __attribute__((address_space(1))) void*)(gx + 1024),
        (__attribute__((address_space(3))) void*)(lx + 1024), 16, 0, 0);
    const unsigned char* gs = Aimg + wid * 8192 + lane * 16;
    unsigned char* ls = abuf + wid * 8192;
#pragma unroll
    for (int i = 0; i < 8; ++i)
      __builtin_amdgcn_global_load_lds(
          (const __attribute__((address_space(1))) void*)(gs + i * 1024),
          (__attribute__((address_space(3))) void*)(ls + i * 1024), 16, 0, 0);
  }

  // B fragments: this wave's 64 x-rows (2 n-tiles), resident all kernel.
  // xf[t][s][j] = x[nbase + nh*64 + t*32 + ln][16s + 8*half + j]
  short8 xf[2][8];
#pragma unroll
  for (int t = 0; t < 2; ++t) {
    const float* xr = x + (size_t)(nbase + nh * 64 + t * 32 + ln) * FD + 8 * half;
#pragma unroll
    for (int s = 0; s < 8; ++s) {
      const float4 a = *(const float4*)(xr + 16 * s);
      const float4 b = *(const float4*)(xr + 16 * s + 4);
      short8 f;
      f[0] = (short)f2bf(a.x); f[1] = (short)f2bf(a.y);
      f[2] = (short)f2bf(a.z); f[3] = (short)f2bf(a.w);
      f[4] = (short)f2bf(b.x); f[5] = (short)f2bf(b.y);
      f[6] = (short)f2bf(b.z); f[7] = (short)f2bf(b.w);
      xf[t][s] = f;
    }
  }

  asm volatile("s_waitcnt vmcnt(0)" ::: "memory");
  __syncthreads();

  // xv[n,k] mini-GEMM for the tile this wave finalizes (t == gh):
  // row k = (i&3)+8*(i>>2)+4*half, col n = nbase + nh*64 + gh*32 + ln
  f32x16 xv;
#pragma unroll
  for (int i = 0; i < 16; ++i) xv[i] = 0.f;
  {
    const unsigned char* xb = abuf + SLABB + lane * 16;
#pragma unroll
    for (int s = 0; s < 8; ++s) {
      const short8 fx = *(const short8*)(xb + s * 1024);
      xv = __builtin_amdgcn_mfma_f32_32x32x16_bf16(fx, gh ? xf[1][s] : xf[0][s], xv, 0, 0, 0);
    }
  }
  asm volatile("s_waitcnt vmcnt(0) lgkmcnt(0)" ::: "memory");
  __syncthreads();  // xv region of buf1 free for reuse; slab0 resident

  float m = -__builtin_inff(), ssum = 0.f;
  comp_iter<0>(Aimg, abuf, xch, ck, wid, gh, lane, half, ln, xf, xv, m, ssum);

  if (half == 0) out[nbase + nh * 64 + gh * 32 + ln] = m + logf(ssum);
}

extern "C" void kernel_launch(void* const* d_in, const int* in_sizes, int n_in,
                              void* d_out, int out_size, void* d_ws, size_t ws_size,
                              hipStream_t stream) {
  const float* x = (const float*)d_in[0];
  const float* means = (const float*)d_in[1];
  const float* P = (const float*)d_in[2];
  const float* w = (const float*)d_in[3];
  float* out = (float*)d_out;

  unsigned char* ws = (unsigned char*)d_ws;
  unsigned char* Aimg = ws;                       // 1048576 B
  unsigned char* Ximg = ws + 1048576;             // 8192 B
  float* mp = (float*)(ws + 1048576 + 8192);      // 16384 B
  float* v = (float*)(ws + 1048576 + 24576);      // 16384 B
  float* ck3 = (float*)(ws + 1048576 + 40960);    // 128 B

  prep1<<<32, 128, 0, stream>>>(means, P, w, mp, ck3);
  prep2<<<32, 128, 0, stream>>>(P, mp, v);
  prep3<<<2, 256, 0, stream>>>(v, Ximg);
  prep4<<<256, 256, 0, stream>>>(P, Aimg);
  gmm_main<<<NPTS / 128, 256, 0, stream>>>(x, Aimg, Ximg, ck3, out);
}

// Round 8
// 100.096 us; speedup vs baseline: 2.0422x; 1.8904x over previous
//
#include <hip/hip_runtime.h>
#include <hip/hip_bf16.h>

// GMM log-likelihood, N=65536, K=32, F=128.
// 1 block/CU (grid 256, launch_bounds(256,1) -> 512 unified regs/wave, no
// spill by construction). Wave (gh,nh) owns 64 g-rows x 128 n-rows:
// 16 ds_read_b128 -> 64 MFMAs per comp (1:4; LDS pipe ~1024 cyc < MFMA 2065
// cyc per CU per comp). B (x) frags xf[4][8] = 128 arch VGPRs; acc 8x f32x16
// = 128 AGPRs. Mean fold via v-trick with xv kept in an LDS table (wave-
// private) -> runtime k-loop, no register cost. Pairwise cross-wave combine
// via 1-float xch slots. One barrier per comp; staged slab K+1 drains under
// ~2000 cyc of MFMA cover.

#define NPTS 65536
#define KC 32
#define FD 128
#define SLABB 32768  // 4 q * 8 s * 64 lanes * 16 B per component

typedef __attribute__((ext_vector_type(8))) short short8;
typedef __attribute__((ext_vector_type(8))) unsigned short ushort8;
typedef __attribute__((ext_vector_type(16))) float f32x16;

#define MFMA(A, B, C) __builtin_amdgcn_mfma_f32_32x32x16_bf16((A), (B), (C), 0, 0, 0)

static __device__ __forceinline__ unsigned short f2bf(float f) {
  unsigned int u = __float_as_uint(f);
  u += 0x7FFFu + ((u >> 16) & 1u);  // RNE
  return (unsigned short)(u >> 16);
}

static __device__ __forceinline__ void gll(const unsigned char* g, unsigned char* l) {
  __builtin_amdgcn_global_load_lds((const __attribute__((address_space(1))) void*)g,
                                   (__attribute__((address_space(3))) void*)l, 16, 0, 0);
}

// --- prep1: mp[k][g] = sum_f means[k][f]*P[k][f][g];
//     ck3[k] = log w + logdet - 0.5*(F*log2pi + sum_g mp^2) ---
__global__ void prep1(const float* __restrict__ means, const float* __restrict__ P,
                      const float* __restrict__ w, float* __restrict__ mp,
                      float* __restrict__ ck3) {
  int k = blockIdx.x, g = threadIdx.x;  // 32 x 128
  const float* Pk = P + k * FD * FD;
  float acc = 0.f;
  for (int f = 0; f < FD; ++f) acc = fmaf(means[k * FD + f], Pk[f * FD + g], acc);
  mp[k * FD + g] = acc;
  __shared__ float r1[FD], r2[FD];
  r1[g] = logf(Pk[g * FD + g]);
  r2[g] = acc * acc;
  __syncthreads();
  for (int off = 64; off; off >>= 1) {
    if (g < off) { r1[g] += r1[g + off]; r2[g] += r2[g + off]; }
    __syncthreads();
  }
  if (g == 0)
    ck3[k] = logf(w[k]) + r1[0] - 0.5f * ((float)FD * 1.8378770664093453f + r2[0]);
}

// --- prep2: v[k][f] = sum_g P[k][f][g] * mp[k][g] ---
__global__ void prep2(const float* __restrict__ P, const float* __restrict__ mp,
                      float* __restrict__ v) {
  int k = blockIdx.x, f = threadIdx.x;  // 32 x 128
  __shared__ float smp[FD];
  smp[f] = mp[k * FD + f];
  __syncthreads();
  const float* Pr = P + k * FD * FD + f * FD;
  float acc = 0.f;
  for (int g = 0; g < FD; ++g) acc = fmaf(Pr[g], smp[g], acc);
  v[k * FD + f] = acc;
}

// --- prep3: xv mini-slab (8 KB): A'[row k][f] = v[k][f], frag-major ---
__global__ void prep3(const float* __restrict__ v, unsigned char* __restrict__ Ximg) {
  int id = blockIdx.x * 256 + threadIdx.x;  // 0..511 chunks
  int l = id & 63, s = id >> 6;
  int r = l & 31, f0 = 16 * s + 8 * (l >> 5);
  ushort8 o;
#pragma unroll
  for (int j = 0; j < 8; ++j) o[j] = f2bf(v[r * FD + f0 + j]);
  *(ushort8*)(Ximg + (size_t)id * 16) = o;
}

// --- prep4: frag-major bf16 A image. chunk id -> (k,q,s,lane). ---
__global__ void prep4(const float* __restrict__ P, unsigned char* __restrict__ Aimg) {
  int id = blockIdx.x * 256 + threadIdx.x;  // 0..65535
  int l = id & 63;
  int s = (id >> 6) & 7;
  int q = (id >> 9) & 3;
  int k = id >> 11;
  int g = q * 32 + (l & 31);
  int f0 = 16 * s + 8 * (l >> 5);
  ushort8 o;
#pragma unroll
  for (int j = 0; j < 8; ++j) o[j] = f2bf(P[k * 16384 + (f0 + j) * 128 + g]);
  *(ushort8*)(Aimg + (size_t)id * 16) = o;
}

// --- main ---
__global__ __launch_bounds__(256, 1) void gmm_main(const float* __restrict__ x,
                                                   const unsigned char* __restrict__ Aimg,
                                                   const unsigned char* __restrict__ Ximg,
                                                   const float* __restrict__ ck3,
                                                   float* __restrict__ out) {
  __shared__ __align__(16) unsigned char abuf[2 * SLABB];
  __shared__ __align__(16) float xvt[4][2][KC][32];  // wave-private xv tables
  __shared__ __align__(16) float xch[2][4][2][32];
  __shared__ float ck[KC];
  const int tid = threadIdx.x;
  const int wid = tid >> 6;
  const int lane = tid & 63;
  const int half = lane >> 5;
  const int ln = lane & 31;
  const int gh = wid & 1;   // g-half this wave owns (g-tiles gh*2, gh*2+1)
  const int nh = wid >> 1;  // n-half (128 x-rows = 4 n-tiles t0..t3)
  const int nbase = blockIdx.x * 256;

  if (tid < KC) ck[tid] = ck3[tid];

  // issue prologue stages: Ximg (8 KB) -> buf1[0:8K], slab0 -> buf0
  {
    const unsigned char* gx = Ximg + wid * 2048 + lane * 16;
    unsigned char* lx = abuf + SLABB + wid * 2048;
    gll(gx, lx);
    gll(gx + 1024, lx + 1024);
    const unsigned char* gs = Aimg + wid * 8192 + lane * 16;
    unsigned char* ls = abuf + wid * 8192;
#pragma unroll
    for (int i = 0; i < 8; ++i) gll(gs + i * 1024, ls + i * 1024);
  }

  // B fragments: this wave's 128 x-rows (4 n-tiles), resident all kernel.
  // xf[t][s][j] = x[nbase + nh*128 + t*32 + ln][16s + 8*half + j]  (128 VGPR)
  short8 xf[4][8];
#pragma unroll
  for (int t = 0; t < 4; ++t) {
    const float* xr = x + (size_t)(nbase + nh * 128 + t * 32 + ln) * FD + 8 * half;
#pragma unroll
    for (int s = 0; s < 8; ++s) {
      const float4 a = *(const float4*)(xr + 16 * s);
      const float4 b = *(const float4*)(xr + 16 * s + 4);
      short8 f;
      f[0] = (short)f2bf(a.x); f[1] = (short)f2bf(a.y);
      f[2] = (short)f2bf(a.z); f[3] = (short)f2bf(a.w);
      f[4] = (short)f2bf(b.x); f[5] = (short)f2bf(b.y);
      f[6] = (short)f2bf(b.z); f[7] = (short)f2bf(b.w);
      xf[t][s] = f;
    }
  }

  asm volatile("s_waitcnt vmcnt(0)" ::: "memory");
  __syncthreads();

  // xv mini-GEMMs for the two n-tiles this wave finalizes (t = 2gh, 2gh+1);
  // result row k = (i&3)+8*(i>>2)+4*half, col n = ln -> dump to LDS table.
  {
    f32x16 zz;
#pragma unroll
    for (int i = 0; i < 16; ++i) zz[i] = 0.f;
    f32x16 xvA = zz, xvB = zz;
    const unsigned char* xb = abuf + SLABB + lane * 16;
    if (gh == 0) {
#pragma unroll
      for (int s = 0; s < 8; ++s) {
        const short8 fx = *(const short8*)(xb + s * 1024);
        xvA = MFMA(fx, xf[0][s], xvA);
        xvB = MFMA(fx, xf[1][s], xvB);
      }
    } else {
#pragma unroll
      for (int s = 0; s < 8; ++s) {
        const short8 fx = *(const short8*)(xb + s * 1024);
        xvA = MFMA(fx, xf[2][s], xvA);
        xvB = MFMA(fx, xf[3][s], xvB);
      }
    }
#pragma unroll
    for (int i = 0; i < 16; ++i) {
      const int kk = (i & 3) + 8 * (i >> 2) + 4 * half;
      xvt[wid][0][kk][ln] = xvA[i];
      xvt[wid][1][kk][ln] = xvB[i];
    }
  }
  asm volatile("s_waitcnt lgkmcnt(0)" ::: "memory");
  __syncthreads();  // buf1's Ximg region free for slab1; xvt resident

  float mA = -__builtin_inff(), ssA = 0.f, mB = -__builtin_inff(), ssB = 0.f;

  for (int k = 0; k < KC; ++k) {
    const int RB = (k & 1) * SLABB;
    const int WB = SLABB - RB;
    const int ph = k & 1;
    if (k + 1 < KC) {  // stage slab K+1 (own quarter; readers finished last comp)
      const unsigned char* gs = Aimg + (size_t)(k + 1) * SLABB + wid * 8192 + lane * 16;
      unsigned char* ls = abuf + WB + wid * 8192;
#pragma unroll
      for (int i = 0; i < 8; ++i) gll(gs + i * 1024, ls + i * 1024);
    }
    const unsigned char* rb = abuf + RB + gh * 16384 + lane * 16;
    short8 fr[8], fr2[8];
#pragma unroll
    for (int s = 0; s < 8; ++s) fr[s] = *(const short8*)(rb + s * 1024);
#pragma unroll
    for (int s = 0; s < 8; ++s) fr2[s] = *(const short8*)(rb + 8192 + s * 1024);
    f32x16 zz;
#pragma unroll
    for (int i = 0; i < 16; ++i) zz[i] = 0.f;
    f32x16 a00 = zz, a01 = zz, a02 = zz, a03 = zz;
    f32x16 a10 = zz, a11 = zz, a12 = zz, a13 = zz;
#pragma unroll
    for (int s = 0; s < 8; ++s) {
      a00 = MFMA(fr[s], xf[0][s], a00);
      a01 = MFMA(fr[s], xf[1][s], a01);
      a02 = MFMA(fr[s], xf[2][s], a02);
      a03 = MFMA(fr[s], xf[3][s], a03);
    }
#pragma unroll
    for (int s = 0; s < 8; ++s) {
      a10 = MFMA(fr2[s], xf[0][s], a10);
      a11 = MFMA(fr2[s], xf[1][s], a11);
      a12 = MFMA(fr2[s], xf[2][s], a12);
      a13 = MFMA(fr2[s], xf[3][s], a13);
    }
    // squares per n-tile over this wave's 64 g
    float q0 = 0.f, q1 = 0.f, q2 = 0.f, q3 = 0.f;
#pragma unroll
    for (int i = 0; i < 16; ++i) {
      q0 = fmaf(a00[i], a00[i], q0); q0 = fmaf(a10[i], a10[i], q0);
      q1 = fmaf(a01[i], a01[i], q1); q1 = fmaf(a11[i], a11[i], q1);
      q2 = fmaf(a02[i], a02[i], q2); q2 = fmaf(a12[i], a12[i], q2);
      q3 = fmaf(a03[i], a03[i], q3); q3 = fmaf(a13[i], a13[i], q3);
    }
    q0 += __shfl_xor(q0, 32, 64);
    q1 += __shfl_xor(q1, 32, 64);
    q2 += __shfl_xor(q2, 32, 64);
    q3 += __shfl_xor(q3, 32, 64);
    float sA = gh ? q2 : q0;  // tiles this wave finalizes (t = 2gh, 2gh+1)
    float sB = gh ? q3 : q1;
    float oA = gh ? q0 : q2;  // tiles the partner (wid^1) finalizes
    float oB = gh ? q1 : q3;
    if (half == 0) { xch[ph][wid ^ 1][0][ln] = oA; xch[ph][wid ^ 1][1][ln] = oB; }
    if (k + 1 < KC) asm volatile("s_waitcnt vmcnt(0)" ::: "memory");
    __syncthreads();  // xch visibility + staging handoff (one barrier/comp)
    sA += xch[ph][wid][0][ln];
    sB += xch[ph][wid][1][ln];
    sA = fmaf(-2.f, xvt[wid][0][k][ln], sA);  // v-trick correction
    sB = fmaf(-2.f, xvt[wid][1][k][ln], sB);
    const float c = ck[k];
    float vA = c - 0.5f * sA;
    float vB = c - 0.5f * sB;
    float nmA = fmaxf(mA, vA);
    ssA = ssA * __expf(mA - nmA) + __expf(vA - nmA);
    mA = nmA;
    float nmB = fmaxf(mB, vB);
    ssB = ssB * __expf(mB - nmB) + __expf(vB - nmB);
    mB = nmB;
  }

  if (half == 0) {
    out[nbase + nh * 128 + (2 * gh) * 32 + ln] = mA + logf(ssA);
    out[nbase + nh * 128 + (2 * gh + 1) * 32 + ln] = mB + logf(ssB);
  }
}

extern "C" void kernel_launch(void* const* d_in, const int* in_sizes, int n_in,
                              void* d_out, int out_size, void* d_ws, size_t ws_size,
                              hipStream_t stream) {
  const float* x = (const float*)d_in[0];
  const float* means = (const float*)d_in[1];
  const float* P = (const float*)d_in[2];
  const float* w = (const float*)d_in[3];
  float* out = (float*)d_out;

  unsigned char* ws = (unsigned char*)d_ws;
  unsigned char* Aimg = ws;                       // 1048576 B
  unsigned char* Ximg = ws + 1048576;             // 8192 B
  float* mp = (float*)(ws + 1048576 + 8192);      // 16384 B
  float* v = (float*)(ws + 1048576 + 24576);      // 16384 B
  float* ck3 = (float*)(ws + 1048576 + 40960);    // 128 B

  prep1<<<32, 128, 0, stream>>>(means, P, w, mp, ck3);
  prep2<<<32, 128, 0, stream>>>(P, mp, v);
  prep3<<<2, 256, 0, stream>>>(v, Ximg);
  prep4<<<256, 256, 0, stream>>>(P, Aimg);
  gmm_main<<<NPTS / 256, 256, 0, stream>>>(x, Aimg, Ximg, ck3, out);
}

// Round 9
// 85.965 us; speedup vs baseline: 2.3778x; 1.1644x over previous
//
#include <hip/hip_runtime.h>
#include <hip/hip_bf16.h>

// GMM log-likelihood, N=65536, K=32, F=128.
// 1 block/CU (grid 256, launch_bounds(256,1) -> 512 unified regs/wave).
// Wave (gh,nh) owns 64 g-rows x 128 n-rows: 16 ds_read_b128 -> 64 MFMAs/comp.
// DEFERRED EPILOGUE: dual accumulator banks (256 AGPR); body k issues MFMAs(k)
// into bank cur, then runs epilogue(k-1) (squares+shfl+xch) from bank prev --
// register-only VALU that the scheduler interleaves into MFMA issue-stall
// slots. LSE(k-1) tail after the barrier fills next comp's ds_read latency.
// Mean fold via v-trick (xv in LDS table). zc C-operand avoids per-comp
// accumulator zero-init. One barrier per comp.

#define NPTS 65536
#define KC 32
#define FD 128
#define SLABB 32768  // 4 q * 8 s * 64 lanes * 16 B per component

typedef __attribute__((ext_vector_type(8))) short short8;
typedef __attribute__((ext_vector_type(8))) unsigned short ushort8;
typedef __attribute__((ext_vector_type(16))) float f32x16;

#define MFMA(A, B, C) __builtin_amdgcn_mfma_f32_32x32x16_bf16((A), (B), (C), 0, 0, 0)

static __device__ __forceinline__ unsigned short f2bf(float f) {
  unsigned int u = __float_as_uint(f);
  u += 0x7FFFu + ((u >> 16) & 1u);  // RNE
  return (unsigned short)(u >> 16);
}

static __device__ __forceinline__ void gll(const unsigned char* g, unsigned char* l) {
  __builtin_amdgcn_global_load_lds((const __attribute__((address_space(1))) void*)g,
                                   (__attribute__((address_space(3))) void*)l, 16, 0, 0);
}

// --- prep12: fused. smp[g] = mu_k @ P_k[:,g]; v[k][f] = P_k[f,:] @ smp;
//     ck3[k] = log w + logdet - 0.5*(F*log2pi + sum_g smp^2) ---
__global__ void prep12(const float* __restrict__ means, const float* __restrict__ P,
                       const float* __restrict__ w, float* __restrict__ v,
                       float* __restrict__ ck3) {
  int k = blockIdx.x, g = threadIdx.x;  // 32 x 128
  const float* Pk = P + k * FD * FD;
  float acc = 0.f;
  for (int f = 0; f < FD; ++f) acc = fmaf(means[k * FD + f], Pk[f * FD + g], acc);
  __shared__ float smp[FD], r1[FD], r2[FD];
  smp[g] = acc;
  r1[g] = logf(Pk[g * FD + g]);
  r2[g] = acc * acc;
  __syncthreads();
  const float* Pr = Pk + g * FD;
  float a2 = 0.f;
  for (int j = 0; j < FD; ++j) a2 = fmaf(Pr[j], smp[j], a2);
  v[k * FD + g] = a2;
  for (int off = 64; off; off >>= 1) {
    if (g < off) { r1[g] += r1[g + off]; r2[g] += r2[g + off]; }
    __syncthreads();
  }
  if (g == 0)
    ck3[k] = logf(w[k]) + r1[0] - 0.5f * ((float)FD * 1.8378770664093453f + r2[0]);
}

// --- prep3: xv mini-slab (8 KB): A'[row k][f] = v[k][f], frag-major ---
__global__ void prep3(const float* __restrict__ v, unsigned char* __restrict__ Ximg) {
  int id = blockIdx.x * 256 + threadIdx.x;  // 0..511 chunks
  int l = id & 63, s = id >> 6;
  int r = l & 31, f0 = 16 * s + 8 * (l >> 5);
  ushort8 o;
#pragma unroll
  for (int j = 0; j < 8; ++j) o[j] = f2bf(v[r * FD + f0 + j]);
  *(ushort8*)(Ximg + (size_t)id * 16) = o;
}

// --- prep4: frag-major bf16 A image. chunk id -> (k,q,s,lane). ---
__global__ void prep4(const float* __restrict__ P, unsigned char* __restrict__ Aimg) {
  int id = blockIdx.x * 256 + threadIdx.x;  // 0..65535
  int l = id & 63;
  int s = (id >> 6) & 7;
  int q = (id >> 9) & 3;
  int k = id >> 11;
  int g = q * 32 + (l & 31);
  int f0 = 16 * s + 8 * (l >> 5);
  ushort8 o;
#pragma unroll
  for (int j = 0; j < 8; ++j) o[j] = f2bf(P[k * 16384 + (f0 + j) * 128 + g]);
  *(ushort8*)(Aimg + (size_t)id * 16) = o;
}

// --- main body: MFMAs(k) -> cur; epilogue(k-1) from prev; 1 barrier ---
template <int RB, bool FIRST, bool LASTK>
__device__ __forceinline__ void body(int k, const unsigned char* __restrict__ Aimg,
                                     unsigned char* abuf, float (&xvt)[4][2][KC][32],
                                     float (&xch)[2][4][2][32], const float* ck,
                                     int wid, int gh, int lane, int half, int ln,
                                     const short8 (&xf)[4][8], const f32x16& zc,
                                     f32x16 (&cur)[8], const f32x16 (&prev)[8],
                                     float& mA, float& ssA, float& mB, float& ssB) {
  constexpr int WB = SLABB - RB;
  constexpr int PH = RB ? 0 : 1;  // xch phase of epilogue(k-1)
  // ds_reads for comp k (slab staged & drained last comp)
  const unsigned char* rb = abuf + RB + gh * 16384 + lane * 16;
  short8 fr[8];
#pragma unroll
  for (int s = 0; s < 8; ++s) fr[s] = *(const short8*)(rb + s * 1024);
  if (!LASTK) {  // stage slab k+1 into the other buffer (own quarter)
    const unsigned char* gs = Aimg + (size_t)(k + 1) * SLABB + wid * 8192 + lane * 16;
    unsigned char* ls = abuf + WB + wid * 8192;
#pragma unroll
    for (int i = 0; i < 8; ++i) gll(gs + i * 1024, ls + i * 1024);
  }
  // group 1: g-tile gh*2 (32 MFMAs), C of first k-slice = zc (no zero-init)
#pragma unroll
  for (int t = 0; t < 4; ++t) cur[t] = MFMA(fr[0], xf[t][0], zc);
#pragma unroll
  for (int s = 1; s < 8; ++s)
#pragma unroll
    for (int t = 0; t < 4; ++t) cur[t] = MFMA(fr[s], xf[t][s], cur[t]);
  // reload frag bank for g-tile gh*2+1 (register budget: single fr bank)
#pragma unroll
  for (int s = 0; s < 8; ++s) fr[s] = *(const short8*)(rb + 8192 + s * 1024);
#pragma unroll
  for (int t = 0; t < 4; ++t) cur[4 + t] = MFMA(fr[0], xf[t][0], zc);
#pragma unroll
  for (int s = 1; s < 8; ++s)
#pragma unroll
    for (int t = 0; t < 4; ++t) cur[4 + t] = MFMA(fr[s], xf[t][s], cur[4 + t]);
  // epilogue of comp k-1 from prev bank (independent of in-flight MFMAs;
  // scheduler interleaves these VALU ops into MFMA issue-stall slots)
  float sA = 0.f, sB = 0.f;
  if (!FIRST) {
    float q0 = 0.f, q1 = 0.f, q2 = 0.f, q3 = 0.f;
#pragma unroll
    for (int i = 0; i < 16; ++i) {
      q0 = fmaf(prev[0][i], prev[0][i], q0); q0 = fmaf(prev[4][i], prev[4][i], q0);
      q1 = fmaf(prev[1][i], prev[1][i], q1); q1 = fmaf(prev[5][i], prev[5][i], q1);
      q2 = fmaf(prev[2][i], prev[2][i], q2); q2 = fmaf(prev[6][i], prev[6][i], q2);
      q3 = fmaf(prev[3][i], prev[3][i], q3); q3 = fmaf(prev[7][i], prev[7][i], q3);
    }
    q0 += __shfl_xor(q0, 32, 64);
    q1 += __shfl_xor(q1, 32, 64);
    q2 += __shfl_xor(q2, 32, 64);
    q3 += __shfl_xor(q3, 32, 64);
    sA = gh ? q2 : q0;  // n-tiles this wave finalizes (t = 2gh, 2gh+1)
    sB = gh ? q3 : q1;
    float oA = gh ? q0 : q2;  // n-tiles the partner (wid^1) finalizes
    float oB = gh ? q1 : q3;
    if (half == 0) { xch[PH][wid ^ 1][0][ln] = oA; xch[PH][wid ^ 1][1][ln] = oB; }
  }
  if (!LASTK) asm volatile("s_waitcnt vmcnt(0)" ::: "memory");
  __syncthreads();  // xch visibility + staging handoff (one barrier/comp)
  if (!FIRST) {  // LSE(k-1) tail; fills next comp's ds_read latency
    sA += xch[PH][wid][0][ln];
    sB += xch[PH][wid][1][ln];
    sA = fmaf(-2.f, xvt[wid][0][k - 1][ln], sA);
    sB = fmaf(-2.f, xvt[wid][1][k - 1][ln], sB);
    const float c = ck[k - 1];
    float vA = c - 0.5f * sA;
    float vB = c - 0.5f * sB;
    float nmA = fmaxf(mA, vA);
    ssA = ssA * __expf(mA - nmA) + __expf(vA - nmA);
    mA = nmA;
    float nmB = fmaxf(mB, vB);
    ssB = ssB * __expf(mB - nmB) + __expf(vB - nmB);
    mB = nmB;
  }
}

__global__ __launch_bounds__(256, 1) void gmm_main(const float* __restrict__ x,
                                                   const unsigned char* __restrict__ Aimg,
                                                   const unsigned char* __restrict__ Ximg,
                                                   const float* __restrict__ ck3,
                                                   float* __restrict__ out) {
  __shared__ __align__(16) unsigned char abuf[2 * SLABB];
  __shared__ __align__(16) float xvt[4][2][KC][32];  // wave-private xv tables
  __shared__ __align__(16) float xch[2][4][2][32];
  __shared__ float ck[KC];
  const int tid = threadIdx.x;
  const int wid = tid >> 6;
  const int lane = tid & 63;
  const int half = lane >> 5;
  const int ln = lane & 31;
  const int gh = wid & 1;   // g-half this wave owns (g-tiles gh*2, gh*2+1)
  const int nh = wid >> 1;  // n-half (128 x-rows = 4 n-tiles t0..t3)
  const int nbase = blockIdx.x * 256;

  if (tid < KC) ck[tid] = ck3[tid];

  // issue prologue stages: Ximg (8 KB) -> buf1[0:8K], slab0 -> buf0
  {
    const unsigned char* gx = Ximg + wid * 2048 + lane * 16;
    unsigned char* lx = abuf + SLABB + wid * 2048;
    gll(gx, lx);
    gll(gx + 1024, lx + 1024);
    const unsigned char* gs = Aimg + wid * 8192 + lane * 16;
    unsigned char* ls = abuf + wid * 8192;
#pragma unroll
    for (int i = 0; i < 8; ++i) gll(gs + i * 1024, ls + i * 1024);
  }

  // B fragments: this wave's 128 x-rows (4 n-tiles), resident all kernel.
  // xf[t][s][j] = x[nbase + nh*128 + t*32 + ln][16s + 8*half + j]  (128 VGPR)
  short8 xf[4][8];
#pragma unroll
  for (int t = 0; t < 4; ++t) {
    const float* xr = x + (size_t)(nbase + nh * 128 + t * 32 + ln) * FD + 8 * half;
#pragma unroll
    for (int s = 0; s < 8; ++s) {
      const float4 a = *(const float4*)(xr + 16 * s);
      const float4 b = *(const float4*)(xr + 16 * s + 4);
      short8 f;
      f[0] = (short)f2bf(a.x); f[1] = (short)f2bf(a.y);
      f[2] = (short)f2bf(a.z); f[3] = (short)f2bf(a.w);
      f[4] = (short)f2bf(b.x); f[5] = (short)f2bf(b.y);
      f[6] = (short)f2bf(b.z); f[7] = (short)f2bf(b.w);
      xf[t][s] = f;
    }
  }

  f32x16 zc;  // persistent zero C-operand
#pragma unroll
  for (int i = 0; i < 16; ++i) zc[i] = 0.f;

  asm volatile("s_waitcnt vmcnt(0)" ::: "memory");
  __syncthreads();

  // xv mini-GEMMs for the two n-tiles this wave finalizes (t = 2gh, 2gh+1);
  // result row k = (i&3)+8*(i>>2)+4*half, col n = ln -> dump to LDS table.
  {
    const unsigned char* xb = abuf + SLABB + lane * 16;
    f32x16 xvA, xvB;
    {
      const short8 fx = *(const short8*)(xb);
      xvA = MFMA(fx, gh ? xf[2][0] : xf[0][0], zc);
      xvB = MFMA(fx, gh ? xf[3][0] : xf[1][0], zc);
    }
#pragma unroll
    for (int s = 1; s < 8; ++s) {
      const short8 fx = *(const short8*)(xb + s * 1024);
      xvA = MFMA(fx, gh ? xf[2][s] : xf[0][s], xvA);
      xvB = MFMA(fx, gh ? xf[3][s] : xf[1][s], xvB);
    }
#pragma unroll
    for (int i = 0; i < 16; ++i) {
      const int kk = (i & 3) + 8 * (i >> 2) + 4 * half;
      xvt[wid][0][kk][ln] = xvA[i];
      xvt[wid][1][kk][ln] = xvB[i];
    }
  }
  __syncthreads();  // buf1's Ximg region free for slab1; xvt resident

  float mA = -__builtin_inff(), ssA = 0.f, mB = -__builtin_inff(), ssB = 0.f;
  f32x16 accA[8], accB[8];

  body<0, true, false>(0, Aimg, abuf, xvt, xch, ck, wid, gh, lane, half, ln, xf, zc,
                       accA, accB, mA, ssA, mB, ssB);
  for (int k2 = 1; k2 <= KC - 3; k2 += 2) {
    body<SLABB, false, false>(k2, Aimg, abuf, xvt, xch, ck, wid, gh, lane, half, ln,
                              xf, zc, accB, accA, mA, ssA, mB, ssB);
    body<0, false, false>(k2 + 1, Aimg, abuf, xvt, xch, ck, wid, gh, lane, half, ln,
                          xf, zc, accA, accB, mA, ssA, mB, ssB);
  }
  body<SLABB, false, true>(KC - 1, Aimg, abuf, xvt, xch, ck, wid, gh, lane, half, ln,
                           xf, zc, accB, accA, mA, ssA, mB, ssB);

  // final epilogue for comp 31 (bank accB), phase 1
  {
    float q0 = 0.f, q1 = 0.f, q2 = 0.f, q3 = 0.f;
#pragma unroll
    for (int i = 0; i < 16; ++i) {
      q0 = fmaf(accB[0][i], accB[0][i], q0); q0 = fmaf(accB[4][i], accB[4][i], q0);
      q1 = fmaf(accB[1][i], accB[1][i], q1); q1 = fmaf(accB[5][i], accB[5][i], q1);
      q2 = fmaf(accB[2][i], accB[2][i], q2); q2 = fmaf(accB[6][i], accB[6][i], q2);
      q3 = fmaf(accB[3][i], accB[3][i], q3); q3 = fmaf(accB[7][i], accB[7][i], q3);
    }
    q0 += __shfl_xor(q0, 32, 64);
    q1 += __shfl_xor(q1, 32, 64);
    q2 += __shfl_xor(q2, 32, 64);
    q3 += __shfl_xor(q3, 32, 64);
    float sA = gh ? q2 : q0;
    float sB = gh ? q3 : q1;
    float oA = gh ? q0 : q2;
    float oB = gh ? q1 : q3;
    if (half == 0) { xch[1][wid ^ 1][0][ln] = oA; xch[1][wid ^ 1][1][ln] = oB; }
    __syncthreads();
    sA += xch[1][wid][0][ln];
    sB += xch[1][wid][1][ln];
    sA = fmaf(-2.f, xvt[wid][0][KC - 1][ln], sA);
    sB = fmaf(-2.f, xvt[wid][1][KC - 1][ln], sB);
    const float c = ck[KC - 1];
    float vA = c - 0.5f * sA;
    float vB = c - 0.5f * sB;
    float nmA = fmaxf(mA, vA);
    ssA = ssA * __expf(mA - nmA) + __expf(vA - nmA);
    mA = nmA;
    float nmB = fmaxf(mB, vB);
    ssB = ssB * __expf(mB - nmB) + __expf(vB - nmB);
    mB = nmB;
  }

  if (half == 0) {
    out[nbase + nh * 128 + (2 * gh) * 32 + ln] = mA + logf(ssA);
    out[nbase + nh * 128 + (2 * gh + 1) * 32 + ln] = mB + logf(ssB);
  }
}

extern "C" void kernel_launch(void* const* d_in, const int* in_sizes, int n_in,
                              void* d_out, int out_size, void* d_ws, size_t ws_size,
                              hipStream_t stream) {
  const float* x = (const float*)d_in[0];
  const float* means = (const float*)d_in[1];
  const float* P = (const float*)d_in[2];
  const float* w = (const float*)d_in[3];
  float* out = (float*)d_out;

  unsigned char* ws = (unsigned char*)d_ws;
  unsigned char* Aimg = ws;                       // 1048576 B
  unsigned char* Ximg = ws + 1048576;             // 8192 B
  float* v = (float*)(ws + 1048576 + 8192);       // 16384 B
  float* ck3 = (float*)(ws + 1048576 + 24576);    // 128 B

  prep12<<<32, 128, 0, stream>>>(means, P, w, v, ck3);
  prep3<<<2, 256, 0, stream>>>(v, Ximg);
  prep4<<<256, 256, 0, stream>>>(P, Aimg);
  gmm_main<<<NPTS / 256, 256, 0, stream>>>(x, Aimg, Ximg, ck3, out);
}

// Round 10
// 79.408 us; speedup vs baseline: 2.5742x; 1.0826x over previous
//
#include <hip/hip_runtime.h>
#include <hip/hip_bf16.h>

// GMM log-likelihood, N=65536, K=32, F=128.
// 2 blocks/CU (grid 512, launch_bounds(256,2) -> 256 unified regs/wave).
// Wave (gh,nh) owns 64 g-rows x 64 n-rows: 16 ds_read_b128 -> 32 MFMAs/comp
// (1:2). Audited register plan ~222/256: xf[2][8]=64, ONE fr[8]=32 (reloaded
// between g-tiles), acc 4x f32x16=64, zc=16, xv=16, temps ~30. Two waves per
// SIMD de-phase between barriers so one wave's epilogue VALU fills the
// other's MFMA pipe slots (the single-wave issue cap was R8/R9's ceiling).
// Mean fold via v-trick (xv in regs, half-uniform via one shfl). zc C-operand
// avoids per-comp acc zero-init. One barrier per comp; stage spans the body.

#define NPTS 65536
#define KC 32
#define FD 128
#define SLABB 32768  // 4 q * 8 s * 64 lanes * 16 B per component

typedef __attribute__((ext_vector_type(8))) short short8;
typedef __attribute__((ext_vector_type(8))) unsigned short ushort8;
typedef __attribute__((ext_vector_type(16))) float f32x16;

#define MFMA(A, B, C) __builtin_amdgcn_mfma_f32_32x32x16_bf16((A), (B), (C), 0, 0, 0)

static __device__ __forceinline__ unsigned short f2bf(float f) {
  unsigned int u = __float_as_uint(f);
  u += 0x7FFFu + ((u >> 16) & 1u);  // RNE
  return (unsigned short)(u >> 16);
}

static __device__ __forceinline__ void gll(const unsigned char* g, unsigned char* l) {
  __builtin_amdgcn_global_load_lds((const __attribute__((address_space(1))) void*)g,
                                   (__attribute__((address_space(3))) void*)l, 16, 0, 0);
}

// --- prep12: fused. smp[g] = mu_k @ P_k[:,g]; v[k][f] = P_k[f,:] @ smp;
//     ck3[k] = log w + logdet - 0.5*(F*log2pi + sum_g smp^2) ---
__global__ void prep12(const float* __restrict__ means, const float* __restrict__ P,
                       const float* __restrict__ w, float* __restrict__ v,
                       float* __restrict__ ck3) {
  int k = blockIdx.x, g = threadIdx.x;  // 32 x 128
  const float* Pk = P + k * FD * FD;
  float acc = 0.f;
  for (int f = 0; f < FD; ++f) acc = fmaf(means[k * FD + f], Pk[f * FD + g], acc);
  __shared__ float smp[FD], r1[FD], r2[FD];
  smp[g] = acc;
  r1[g] = logf(Pk[g * FD + g]);
  r2[g] = acc * acc;
  __syncthreads();
  const float* Pr = Pk + g * FD;
  float a2 = 0.f;
  for (int j = 0; j < FD; ++j) a2 = fmaf(Pr[j], smp[j], a2);
  v[k * FD + g] = a2;
  for (int off = 64; off; off >>= 1) {
    if (g < off) { r1[g] += r1[g + off]; r2[g] += r2[g + off]; }
    __syncthreads();
  }
  if (g == 0)
    ck3[k] = logf(w[k]) + r1[0] - 0.5f * ((float)FD * 1.8378770664093453f + r2[0]);
}

// --- prep3: xv mini-slab (8 KB): A'[row k][f] = v[k][f], frag-major ---
__global__ void prep3(const float* __restrict__ v, unsigned char* __restrict__ Ximg) {
  int id = blockIdx.x * 256 + threadIdx.x;  // 0..511 chunks
  int l = id & 63, s = id >> 6;
  int r = l & 31, f0 = 16 * s + 8 * (l >> 5);
  ushort8 o;
#pragma unroll
  for (int j = 0; j < 8; ++j) o[j] = f2bf(v[r * FD + f0 + j]);
  *(ushort8*)(Ximg + (size_t)id * 16) = o;
}

// --- prep4: frag-major bf16 A image. chunk id -> (k,q,s,lane). ---
__global__ void prep4(const float* __restrict__ P, unsigned char* __restrict__ Aimg) {
  int id = blockIdx.x * 256 + threadIdx.x;  // 0..65535
  int l = id & 63;
  int s = (id >> 6) & 7;
  int q = (id >> 9) & 3;
  int k = id >> 11;
  int g = q * 32 + (l & 31);
  int f0 = 16 * s + 8 * (l >> 5);
  ushort8 o;
#pragma unroll
  for (int j = 0; j < 8; ++j) o[j] = f2bf(P[k * 16384 + (f0 + j) * 128 + g]);
  *(ushort8*)(Aimg + (size_t)id * 16) = o;
}

// --- main ---
__global__ __launch_bounds__(256, 2) void gmm_main(const float* __restrict__ x,
                                                   const unsigned char* __restrict__ Aimg,
                                                   const unsigned char* __restrict__ Ximg,
                                                   const float* __restrict__ ck3,
                                                   float* __restrict__ out) {
  __shared__ __align__(16) unsigned char abuf[2 * SLABB];
  __shared__ __align__(16) float xch[2][4][32];
  __shared__ float ck[KC];
  const int tid = threadIdx.x;
  const int wid = tid >> 6;
  const int lane = tid & 63;
  const int half = lane >> 5;
  const int ln = lane & 31;
  const int gh = wid & 1;   // g-half this wave owns (g-tiles gh*2, gh*2+1)
  const int nh = wid >> 1;  // n-half this wave owns (64 x-rows, tiles t=0,1)
  const int nbase = blockIdx.x * 128;

  if (tid < KC) ck[tid] = ck3[tid];

  // issue prologue stages: Ximg (8 KB) -> buf1[0:8K], slab0 -> buf0
  {
    const unsigned char* gx = Ximg + wid * 2048 + lane * 16;
    unsigned char* lx = abuf + SLABB + wid * 2048;
    gll(gx, lx);
    gll(gx + 1024, lx + 1024);
    const unsigned char* gs = Aimg + wid * 8192 + lane * 16;
    unsigned char* ls = abuf + wid * 8192;
#pragma unroll
    for (int i = 0; i < 8; ++i) gll(gs + i * 1024, ls + i * 1024);
  }

  // B fragments: this wave's 64 x-rows (2 n-tiles), resident all kernel.
  // xf[t][s][j] = x[nbase + nh*64 + t*32 + ln][16s + 8*half + j]  (64 VGPR)
  short8 xf[2][8];
#pragma unroll
  for (int t = 0; t < 2; ++t) {
    const float* xr = x + (size_t)(nbase + nh * 64 + t * 32 + ln) * FD + 8 * half;
#pragma unroll
    for (int s = 0; s < 8; ++s) {
      const float4 a = *(const float4*)(xr + 16 * s);
      const float4 b = *(const float4*)(xr + 16 * s + 4);
      short8 f;
      f[0] = (short)f2bf(a.x); f[1] = (short)f2bf(a.y);
      f[2] = (short)f2bf(a.z); f[3] = (short)f2bf(a.w);
      f[4] = (short)f2bf(b.x); f[5] = (short)f2bf(b.y);
      f[6] = (short)f2bf(b.z); f[7] = (short)f2bf(b.w);
      xf[t][s] = f;
    }
  }

  f32x16 zc;  // persistent zero C-operand (16 regs, saves 64 inits/comp)
#pragma unroll
  for (int i = 0; i < 16; ++i) zc[i] = 0.f;

  asm volatile("s_waitcnt vmcnt(0)" ::: "memory");
  __syncthreads();

  // xv[n,k] mini-GEMM for the n-tile this wave finalizes (t == gh):
  // row k = (i&3)+8*(i>>2)+4*half, col n = nbase + nh*64 + gh*32 + ln
  f32x16 xv;
  {
    const unsigned char* xb = abuf + SLABB + lane * 16;
    {
      const short8 fx = *(const short8*)xb;
      xv = MFMA(fx, gh ? xf[1][0] : xf[0][0], zc);
    }
#pragma unroll
    for (int s = 1; s < 8; ++s) {
      const short8 fx = *(const short8*)(xb + s * 1024);
      xv = MFMA(fx, gh ? xf[1][s] : xf[0][s], xv);
    }
  }
  __syncthreads();  // buf1's Ximg region free for slab1; slab0 resident

  float m = -__builtin_inff(), ssum = 0.f;

  for (int k = 0; k < KC; ++k) {
    const int RB = (k & 1) * SLABB;
    const int WB = SLABB - RB;
    const int ph = k & 1;
    // ds_reads for g-tile gh*2 (single fr bank, reused)
    const unsigned char* rb = abuf + RB + gh * 16384 + lane * 16;
    short8 fr[8];
#pragma unroll
    for (int s = 0; s < 8; ++s) fr[s] = *(const short8*)(rb + s * 1024);
    if (k + 1 < KC) {  // stage slab k+1 into the other buffer (own quarter)
      const unsigned char* gs = Aimg + (size_t)(k + 1) * SLABB + wid * 8192 + lane * 16;
      unsigned char* ls = abuf + WB + wid * 8192;
#pragma unroll
      for (int i = 0; i < 8; ++i) gll(gs + i * 1024, ls + i * 1024);
    }
    __builtin_amdgcn_s_setprio(1);
    f32x16 a00 = MFMA(fr[0], xf[0][0], zc);
    f32x16 a01 = MFMA(fr[0], xf[1][0], zc);
#pragma unroll
    for (int s = 1; s < 8; ++s) {
      a00 = MFMA(fr[s], xf[0][s], a00);
      a01 = MFMA(fr[s], xf[1][s], a01);
    }
    // reload fr bank for g-tile gh*2+1
#pragma unroll
    for (int s = 0; s < 8; ++s) fr[s] = *(const short8*)(rb + 8192 + s * 1024);
    f32x16 a10 = MFMA(fr[0], xf[0][0], zc);
    f32x16 a11 = MFMA(fr[0], xf[1][0], zc);
#pragma unroll
    for (int s = 1; s < 8; ++s) {
      a10 = MFMA(fr[s], xf[0][s], a10);
      a11 = MFMA(fr[s], xf[1][s], a11);
    }
    __builtin_amdgcn_s_setprio(0);
    // epilogue: per-n-tile squares over this wave's 64 g
    float q0a = 0.f, q0b = 0.f, q1a = 0.f, q1b = 0.f;
#pragma unroll
    for (int i = 0; i < 16; ++i) {
      q0a = fmaf(a00[i], a00[i], q0a);
      q0b = fmaf(a10[i], a10[i], q0b);
      q1a = fmaf(a01[i], a01[i], q1a);
      q1b = fmaf(a11[i], a11[i], q1b);
    }
    float q0 = q0a + q0b, q1 = q1a + q1b;
    q0 += __shfl_xor(q0, 32, 64);  // both halves hold full 64-g partials
    q1 += __shfl_xor(q1, 32, 64);
    float sown = gh ? q1 : q0;  // n-tile this wave finalizes (t == gh)
    float soth = gh ? q0 : q1;  // n-tile the partner (wid^1) finalizes
    if (half == 0) xch[ph][wid ^ 1][ln] = soth;
    if (k + 1 < KC) asm volatile("s_waitcnt vmcnt(0)" ::: "memory");
    __syncthreads();  // xch visibility + staging handoff (one barrier/comp)
    float sfull = sown + xch[ph][wid][ln];
    // -2 * x.v_k, made half-uniform with one shfl
    const int owner = (k >> 2) & 1;
    const int idx = (k & 3) | ((k >> 3) << 2);
    float tx = (half == owner) ? xv[idx] : 0.f;
    tx += __shfl_xor(tx, 32, 64);
    sfull = fmaf(-2.f, tx, sfull);
    float vv = ck[k] - 0.5f * sfull;
    float nm = fmaxf(m, vv);
    ssum = ssum * __expf(m - nm) + __expf(vv - nm);
    m = nm;
  }

  if (half == 0) out[nbase + nh * 64 + gh * 32 + ln] = m + logf(ssum);
}

extern "C" void kernel_launch(void* const* d_in, const int* in_sizes, int n_in,
                              void* d_out, int out_size, void* d_ws, size_t ws_size,
                              hipStream_t stream) {
  const float* x = (const float*)d_in[0];
  const float* means = (const float*)d_in[1];
  const float* P = (const float*)d_in[2];
  const float* w = (const float*)d_in[3];
  float* out = (float*)d_out;

  unsigned char* ws = (unsigned char*)d_ws;
  unsigned char* Aimg = ws;                       // 1048576 B
  unsigned char* Ximg = ws + 1048576;             // 8192 B
  float* v = (float*)(ws + 1048576 + 8192);       // 16384 B
  float* ck3 = (float*)(ws + 1048576 + 24576);    // 128 B

  prep12<<<32, 128, 0, stream>>>(means, P, w, v, ck3);
  prep3<<<2, 256, 0, stream>>>(v, Ximg);
  prep4<<<256, 256, 0, stream>>>(P, Aimg);
  gmm_main<<<NPTS / 128, 256, 0, stream>>>(x, Aimg, Ximg, ck3, out);
}